// Round 1
// baseline (1143.080 us; speedup 1.0000x reference)
//
#include <hip/hip_runtime.h>

#define B 32
#define C 16
#define H 256
#define W 256
#define HID 128
#define HW (H*W)
#define ROWS 16

// ---- order-preserving float <-> uint key for atomic min/max ----
__device__ __forceinline__ unsigned fkey(float f){
  unsigned u = __float_as_uint(f);
  return (u & 0x80000000u) ? ~u : (u | 0x80000000u);
}
__device__ __forceinline__ float fkeyinv(unsigned k){
  unsigned u = (k & 0x80000000u) ? (k & 0x7FFFFFFFu) : ~k;
  return __uint_as_float(u);
}

// mm layout: [0..15]=gx_min [16..31]=gx_max [32..47]=gy_min [48..63]=gy_max
__global__ void k_init(unsigned* __restrict__ mm){
  int t = threadIdx.x;
  if (t < 64) mm[t] = (t < 16 || (t >= 32 && t < 48)) ? 0xFFFFFFFFu : 0u;
}

__global__ __launch_bounds__(256) void k_minmax(const float* __restrict__ x,
                                                unsigned* __restrict__ mm){
  const int chunks = H / ROWS;            // 16
  int blk = blockIdx.x;
  int rc  = blk % chunks;
  int bc  = blk / chunks;                 // b*C + c
  int c   = bc % C;
  const float* p = x + (size_t)bc * HW;
  int j = threadIdx.x;
  bool jl = j > 0, jr = j < W-1;

  float gxmn = 1e30f, gxmx = -1e30f, gymn = 1e30f, gymx = -1e30f;
  for (int r = 0; r < ROWS; ++r){
    int i = rc * ROWS + r;
    int im = i-1, ip = i+1;
    bool iu = im >= 0, id = ip < H;
    const float* r0 = p + im*W;
    const float* r1 = p + i*W;
    const float* r2 = p + ip*W;
    float v00 = (iu&&jl) ? r0[j-1] : 0.f;
    float v01 =  iu      ? r0[j]   : 0.f;
    float v02 = (iu&&jr) ? r0[j+1] : 0.f;
    float v10 =  jl      ? r1[j-1] : 0.f;
    float v12 =  jr      ? r1[j+1] : 0.f;
    float v20 = (id&&jl) ? r2[j-1] : 0.f;
    float v21 =  id      ? r2[j]   : 0.f;
    float v22 = (id&&jr) ? r2[j+1] : 0.f;
    // cross-correlation (XLA conv does not flip kernels)
    float gx = (v02 - v00 + 2.f*(v12 - v10) + v22 - v20) * 0.125f;
    float gy = (v20 - v00 + 2.f*(v21 - v01) + v22 - v02) * 0.125f;
    gxmn = fminf(gxmn, gx); gxmx = fmaxf(gxmx, gx);
    gymn = fminf(gymn, gy); gymx = fmaxf(gymx, gy);
  }
  // 64-lane reduce
  for (int off = 32; off; off >>= 1){
    gxmn = fminf(gxmn, __shfl_down(gxmn, off));
    gxmx = fmaxf(gxmx, __shfl_down(gxmx, off));
    gymn = fminf(gymn, __shfl_down(gymn, off));
    gymx = fmaxf(gymx, __shfl_down(gymx, off));
  }
  __shared__ float s[4][4];
  int lane = threadIdx.x & 63, wv = threadIdx.x >> 6;
  if (lane == 0){ s[wv][0]=gxmn; s[wv][1]=gxmx; s[wv][2]=gymn; s[wv][3]=gymx; }
  __syncthreads();
  if (threadIdx.x == 0){
    float a = s[0][0], bx = s[0][1], cm = s[0][2], dm = s[0][3];
    for (int wq = 1; wq < 4; ++wq){
      a  = fminf(a,  s[wq][0]); bx = fmaxf(bx, s[wq][1]);
      cm = fminf(cm, s[wq][2]); dm = fmaxf(dm, s[wq][3]);
    }
    atomicMin(&mm[c],      fkey(a));
    atomicMax(&mm[16+c],   fkey(bx));
    atomicMin(&mm[32+c],   fkey(cm));
    atomicMax(&mm[48+c],   fkey(dm));
  }
}

__global__ __launch_bounds__(256) void k_main(
    const float* __restrict__ x,  const float* __restrict__ w1,
    const float* __restrict__ b1, const float* __restrict__ w2,
    const float* __restrict__ mrand, const unsigned* __restrict__ mm,
    float* __restrict__ out, float* __restrict__ alpha_new)
{
  int blk = blockIdx.x;                 // b*H + i
  int i = blk % H, b = blk / H;
  int j = threadIdx.x;

  __shared__ float amn_x[16], inv_x[16], amn_y[16], inv_y[16];
  if (threadIdx.x < 16){
    int c = threadIdx.x;
    float mn = fabsf(fkeyinv(mm[c]));
    float mx = fabsf(fkeyinv(mm[16+c]));
    float dv = mn + mx;
    amn_x[c] = mn; inv_x[c] = (dv == 0.f) ? 1.f : 1.f/dv;
    mn = fabsf(fkeyinv(mm[32+c]));
    mx = fabsf(fkeyinv(mm[48+c]));
    dv = mn + mx;
    amn_y[c] = mn; inv_y[c] = (dv == 0.f) ? 1.f : 1.f/dv;
  }
  __syncthreads();

  const float* xb = x + (size_t)b * C * HW;
  int im = i-1, ip = i+1;
  bool iu = im >= 0, id = ip < H;
  bool jl = j > 0, jr = j < W-1;

  float y[48];
  float xc[16];
  #pragma unroll
  for (int c = 0; c < 16; ++c){
    const float* pc = xb + (size_t)c * HW;
    const float* r0 = pc + im*W;
    const float* r1 = pc + i*W;
    const float* r2 = pc + ip*W;
    float v00 = (iu&&jl) ? r0[j-1] : 0.f;
    float v01 =  iu      ? r0[j]   : 0.f;
    float v02 = (iu&&jr) ? r0[j+1] : 0.f;
    float v10 =  jl      ? r1[j-1] : 0.f;
    float v11 =            r1[j];
    float v12 =  jr      ? r1[j+1] : 0.f;
    float v20 = (id&&jl) ? r2[j-1] : 0.f;
    float v21 =  id      ? r2[j]   : 0.f;
    float v22 = (id&&jr) ? r2[j+1] : 0.f;
    float gx = (v02 - v00 + 2.f*(v12 - v10) + v22 - v20) * 0.125f;
    float gy = (v20 - v00 + 2.f*(v21 - v01) + v22 - v02) * 0.125f;
    float gl = (v01 + v10 + v12 + v21 - 4.f*v11) * 0.125f;
    float gxn = (gx + amn_x[c]) * inv_x[c];
    float gyn = (gy + amn_y[c]) * inv_y[c];
    xc[c]   = v11;
    y[c]    = v11;
    y[16+c] = gl;
    y[32+c] = sqrtf(gxn*gxn + gyn*gyn);
  }

  float dacc[16];
  #pragma unroll
  for (int m = 0; m < 16; ++m) dacc[m] = 0.f;

  for (int o = 0; o < HID; ++o){
    float a = b1[o];                     // uniform -> s_load
    const float* wr = w1 + o*48;
    #pragma unroll
    for (int k = 0; k < 48; ++k) a = fmaf(y[k], wr[k], a);
    a = fmaxf(a, 0.f);
    #pragma unroll
    for (int m = 0; m < 16; ++m) dacc[m] = fmaf(a, w2[m*HID+o], dacc[m]);
  }

  float fr = (mrand[(size_t)b*HW + i*W + j] <= 0.5f) ? 1.f : 0.f;
  size_t px = (size_t)b*C*HW + (size_t)i*W + j;
  #pragma unroll
  for (int m = 0; m < 16; ++m){
    float xn = xc[m] + dacc[m]*fr;
    out[px + (size_t)m*HW] = xn;
    if (m == 3) alpha_new[(size_t)b*HW + (size_t)i*W + j] = xn;
  }
}

__global__ __launch_bounds__(256) void k_life(
    const float* __restrict__ x, const float* __restrict__ alpha_new,
    float* __restrict__ out)
{
  int blk = blockIdx.x;
  int i = blk % H, b = blk / H;
  int j = threadIdx.x;
  const float* ax = x + ((size_t)b*C + 3)*HW;
  const float* an = alpha_new + (size_t)b*HW;
  float mpre = -1e30f, mpost = -1e30f;
  for (int di = -1; di <= 1; ++di){
    int ii = i + di; if (ii < 0 || ii >= H) continue;
    for (int dj = -1; dj <= 1; ++dj){
      int jj = j + dj; if (jj < 0 || jj >= W) continue;
      mpre  = fmaxf(mpre,  ax[ii*W+jj]);
      mpost = fmaxf(mpost, an[ii*W+jj]);
    }
  }
  bool life = (mpre > 0.1f) && (mpost > 0.1f);
  if (!life){
    size_t px = (size_t)b*C*HW + (size_t)i*W + j;
    #pragma unroll
    for (int m = 0; m < 16; ++m) out[px + (size_t)m*HW] = 0.f;
  }
}

extern "C" void kernel_launch(void* const* d_in, const int* in_sizes, int n_in,
                              void* d_out, int out_size, void* d_ws, size_t ws_size,
                              hipStream_t stream) {
  const float* x  = (const float*)d_in[0];
  const float* w1 = (const float*)d_in[1];
  const float* b1 = (const float*)d_in[2];
  const float* w2 = (const float*)d_in[3];
  const float* mr = (const float*)d_in[4];
  unsigned* mm    = (unsigned*)d_ws;
  float* alpha_n  = (float*)((char*)d_ws + 256);
  float* out      = (float*)d_out;

  k_init  <<<1, 64, 0, stream>>>(mm);
  k_minmax<<<B*C*(H/ROWS), 256, 0, stream>>>(x, mm);
  k_main  <<<B*H, 256, 0, stream>>>(x, w1, b1, w2, mr, mm, out, alpha_n);
  k_life  <<<B*H, 256, 0, stream>>>(x, alpha_n, out);
}

// Round 5
// 592.466 us; speedup vs baseline: 1.9294x; 1.9294x over previous
//
#include <hip/hip_runtime.h>

#define B 32
#define C 16
#define H 256
#define W 256
#define HID 128
#define HW (H*W)
#define ROWS 16

typedef __attribute__((ext_vector_type(8))) _Float16 f16x8;
typedef __attribute__((ext_vector_type(4))) _Float16 f16x4;
typedef __attribute__((ext_vector_type(4))) float f32x4;

// ---- order-preserving float <-> uint key for atomic min/max ----
__device__ __forceinline__ unsigned fkey(float f){
  unsigned u = __float_as_uint(f);
  return (u & 0x80000000u) ? ~u : (u | 0x80000000u);
}
__device__ __forceinline__ float fkeyinv(unsigned k){
  unsigned u = (k & 0x80000000u) ? (k & 0x7FFFFFFFu) : ~k;
  return __uint_as_float(u);
}

// fp16 hi/lo split: v = hi + lo + O(2^-24 |v|)  (lo's re-rounding is the only loss)
__device__ __forceinline__ void fsplit(float v, _Float16& h, _Float16& l){
  h = (_Float16)v;
  l = (_Float16)(v - (float)h);
}

// k_prep: init mm + fragment-ordered fp16 hi/lo weights, K padded to 64.
// x32 A frag: lane l holds M=l&15, K=kblk*32 + 8*(l>>4) + j (j=0..7 contiguous)
// w1k[(ot*2+kblk)*512 + l*8 + j]; k>=48 -> 0
// w2 frags: s=0..3, K=o=32s+8*(l>>4)+j
__global__ __launch_bounds__(256) void k_prep(
    const float* __restrict__ w1, const float* __restrict__ w2,
    unsigned* __restrict__ mm,
    _Float16* __restrict__ w1kh, _Float16* __restrict__ w1kl,
    _Float16* __restrict__ w2h,  _Float16* __restrict__ w2l)
{
  int tid = threadIdx.x;
  if (tid < 64) mm[tid] = (tid < 16 || (tid >= 32 && tid < 48)) ? 0xFFFFFFFFu : 0u;
  for (int e = tid; e < 8192; e += 256){
    int j = e & 7, l = (e >> 3) & 63, otk = e >> 9;     // otk = ot*2 + kblk
    int o = 16*(otk >> 1) + (l & 15);
    int k = (otk & 1)*32 + 8*(l >> 4) + j;
    float v = (k < 48) ? w1[o*48 + k] : 0.f;
    _Float16 h, lo; fsplit(v, h, lo); w1kh[e] = h; w1kl[e] = lo;
  }
  for (int e = tid; e < 2048; e += 256){
    int j = e & 7, l = (e >> 3) & 63, s = e >> 9;
    float v = w2[(l & 15)*128 + 32*s + 8*(l >> 4) + j];
    _Float16 h, lo; fsplit(v, h, lo); w2h[e] = h; w2l[e] = lo;
  }
}

// mm layout: [0..15]=gx_min [16..31]=gx_max [32..47]=gy_min [48..63]=gy_max
__global__ __launch_bounds__(256) void k_minmax(const float* __restrict__ x,
                                                unsigned* __restrict__ mm){
  const int chunks = H / ROWS;
  int blk = blockIdx.x;
  int rc  = blk % chunks;
  int bc  = blk / chunks;
  int c   = bc % C;
  const float* p = x + (size_t)bc * HW;
  int j = threadIdx.x;
  bool jl = j > 0, jr = j < W-1;
  int i0 = rc * ROWS;

  float a0,a1,a2, b0,b1r,b2, c0,c1,c2;
  if (i0 > 0){ const float* r = p + (i0-1)*W;
    a0 = jl ? r[j-1] : 0.f; a1 = r[j]; a2 = jr ? r[j+1] : 0.f;
  } else { a0 = a1 = a2 = 0.f; }
  { const float* r = p + i0*W;
    b0 = jl ? r[j-1] : 0.f; b1r = r[j]; b2 = jr ? r[j+1] : 0.f; }

  float gxmn = 1e30f, gxmx = -1e30f, gymn = 1e30f, gymx = -1e30f;
  for (int r = 0; r < ROWS; ++r){
    int ip = i0 + r + 1;
    if (ip < H){ const float* rw = p + ip*W;
      c0 = jl ? rw[j-1] : 0.f; c1 = rw[j]; c2 = jr ? rw[j+1] : 0.f;
    } else { c0 = c1 = c2 = 0.f; }
    float gx = (a2 - a0 + 2.f*(b2 - b0) + c2 - c0) * 0.125f;
    float gy = (c0 - a0 + 2.f*(c1 - a1) + c2 - a2) * 0.125f;
    gxmn = fminf(gxmn, gx); gxmx = fmaxf(gxmx, gx);
    gymn = fminf(gymn, gy); gymx = fmaxf(gymx, gy);
    a0 = b0; a1 = b1r; a2 = b2;
    b0 = c0; b1r = c1; b2 = c2;
  }
  for (int off = 32; off; off >>= 1){
    gxmn = fminf(gxmn, __shfl_down(gxmn, off));
    gxmx = fmaxf(gxmx, __shfl_down(gxmx, off));
    gymn = fminf(gymn, __shfl_down(gymn, off));
    gymx = fmaxf(gymx, __shfl_down(gymx, off));
  }
  __shared__ float s[4][4];
  int lane = threadIdx.x & 63, wv = threadIdx.x >> 6;
  if (lane == 0){ s[wv][0]=gxmn; s[wv][1]=gxmx; s[wv][2]=gymn; s[wv][3]=gymx; }
  __syncthreads();
  if (threadIdx.x == 0){
    float a = s[0][0], bx = s[0][1], cm = s[0][2], dm = s[0][3];
    for (int wq = 1; wq < 4; ++wq){
      a  = fminf(a,  s[wq][0]); bx = fmaxf(bx, s[wq][1]);
      cm = fminf(cm, s[wq][2]); dm = fmaxf(dm, s[wq][3]);
    }
    atomicMin(&mm[c],      fkey(a));
    atomicMax(&mm[16+c],   fkey(bx));
    atomicMin(&mm[32+c],   fkey(cm));
    atomicMax(&mm[48+c],   fkey(dm));
  }
}

// 128 threads = 2 waves; block handles half a row (128 pixels).
__global__ __launch_bounds__(128) void k_main(
    const float* __restrict__ x, const float* __restrict__ mrand,
    const unsigned* __restrict__ mm,
    const _Float16* __restrict__ w1kh, const _Float16* __restrict__ w1kl,
    const _Float16* __restrict__ w2h,  const _Float16* __restrict__ w2l,
    const float* __restrict__ b1,
    float* __restrict__ out, float* __restrict__ alpha_new)
{
  // 68-col rows (136 B): row bank-starts stride 2 -> only free 2-way overlap
  __shared__ __align__(16) _Float16 ybh_hi[128][68];   // 17.0 KB
  __shared__ __align__(16) _Float16 ybh_lo[128][68];   // 17.0 KB
  __shared__ __align__(16) _Float16 hb_hi[2][16][136]; // 8.7 KB
  __shared__ __align__(16) _Float16 hb_lo[2][16][136]; // 8.7 KB
  __shared__ float amn_x[16], inv_x[16], amn_y[16], inv_y[16];

  const int tid  = threadIdx.x;
  const int blk  = blockIdx.x;
  const int half = blk & 1;
  const int rowid = blk >> 1;            // b*H + i
  const int i = rowid % H, b = rowid / H;
  const int lane = tid & 63, wvid = tid >> 6;
  const int q = lane >> 4, n16 = lane & 15;
  const int j0 = half * 128;

  if (tid < 16){
    int c = tid;
    float mn = fabsf(fkeyinv(mm[c]));
    float mx = fabsf(fkeyinv(mm[16+c]));
    float dv = mn + mx;
    amn_x[c] = mn; inv_x[c] = (dv == 0.f) ? 1.f : 1.f/dv;
    mn = fabsf(fkeyinv(mm[32+c]));
    mx = fabsf(fkeyinv(mm[48+c]));
    dv = mn + mx;
    amn_y[c] = mn; inv_y[c] = (dv == 0.f) ? 1.f : 1.f/dv;
  }
  __syncthreads();

  // ---- stencil: thread = pixel j0+tid; y[48] (+16 zero pad) as fp16 hi/lo ----
  {
    const float* xb = x + (size_t)b * C * HW;
    const int j = j0 + tid;
    const int im = i-1, ip = i+1;
    const bool iu = im >= 0, id = ip < H, jl = j > 0, jr = j < W-1;
    #pragma unroll
    for (int hp = 0; hp < 2; ++hp){
      float xv[8], lv[8], mv[8];
      #pragma unroll
      for (int cc = 0; cc < 8; ++cc){
        const int c = hp*8 + cc;
        const float* pc = xb + (size_t)c * HW;
        const float* r0 = pc + im*W;
        const float* r1 = pc + i*W;
        const float* r2 = pc + ip*W;
        float v00 = (iu&&jl) ? r0[j-1] : 0.f;
        float v01 =  iu      ? r0[j]   : 0.f;
        float v02 = (iu&&jr) ? r0[j+1] : 0.f;
        float v10 =  jl      ? r1[j-1] : 0.f;
        float v11 =            r1[j];
        float v12 =  jr      ? r1[j+1] : 0.f;
        float v20 = (id&&jl) ? r2[j-1] : 0.f;
        float v21 =  id      ? r2[j]   : 0.f;
        float v22 = (id&&jr) ? r2[j+1] : 0.f;
        float gx = (v02 - v00 + 2.f*(v12 - v10) + v22 - v20) * 0.125f;
        float gy = (v20 - v00 + 2.f*(v21 - v01) + v22 - v02) * 0.125f;
        float gl = (v01 + v10 + v12 + v21 - 4.f*v11) * 0.125f;
        float gxn = (gx + amn_x[c]) * inv_x[c];
        float gyn = (gy + amn_y[c]) * inv_y[c];
        xv[cc] = v11;
        lv[cc] = gl;
        mv[cc] = sqrtf(gxn*gxn + gyn*gyn);
      }
      f16x8 vh, vl;
      #pragma unroll
      for (int e = 0; e < 8; ++e){ _Float16 h = (_Float16)xv[e]; vh[e] = h; vl[e] = (_Float16)(xv[e] - (float)h); }
      *(f16x8*)(&ybh_hi[tid][hp*8]) = vh; *(f16x8*)(&ybh_lo[tid][hp*8]) = vl;
      #pragma unroll
      for (int e = 0; e < 8; ++e){ _Float16 h = (_Float16)lv[e]; vh[e] = h; vl[e] = (_Float16)(lv[e] - (float)h); }
      *(f16x8*)(&ybh_hi[tid][16+hp*8]) = vh; *(f16x8*)(&ybh_lo[tid][16+hp*8]) = vl;
      #pragma unroll
      for (int e = 0; e < 8; ++e){ _Float16 h = (_Float16)mv[e]; vh[e] = h; vl[e] = (_Float16)(mv[e] - (float)h); }
      *(f16x8*)(&ybh_hi[tid][32+hp*8]) = vh; *(f16x8*)(&ybh_lo[tid][32+hp*8]) = vl;
    }
    f16x8 z;
    #pragma unroll
    for (int e = 0; e < 8; ++e) z[e] = (_Float16)0.f;
    *(f16x8*)(&ybh_hi[tid][48]) = z; *(f16x8*)(&ybh_lo[tid][48]) = z;
    *(f16x8*)(&ybh_hi[tid][56]) = z; *(f16x8*)(&ybh_lo[tid][56]) = z;
  }
  // y rows and hb slabs are wave-private; per-wave LDS ops are in order -> no barrier.

  // ---- A fragments (L2/L1-hot) + bias ----
  f16x8 A1h[8][2], A1l[8][2];
  #pragma unroll
  for (int ot = 0; ot < 8; ++ot)
    #pragma unroll
    for (int kb = 0; kb < 2; ++kb){
      A1h[ot][kb] = *(const f16x8*)(w1kh + (ot*2+kb)*512 + lane*8);
      A1l[ot][kb] = *(const f16x8*)(w1kl + (ot*2+kb)*512 + lane*8);
    }
  f16x8 A2h[4], A2l[4];
  #pragma unroll
  for (int s = 0; s < 4; ++s){
    A2h[s] = *(const f16x8*)(w2h + s*512 + lane*8);
    A2l[s] = *(const f16x8*)(w2l + s*512 + lane*8);
  }
  f32x4 b1q[8];
  #pragma unroll
  for (int ot = 0; ot < 8; ++ot)
    b1q[ot] = *(const f32x4*)(b1 + 16*ot + 4*q);   // acc rows o=16ot+4q+r

  const size_t rowbase = (size_t)b*C*HW + (size_t)i*W;
  const float* mr_row = mrand + (size_t)b*HW + (size_t)i*W + j0;

  // ---- per-wave: 4 groups of 16 pixels ----
  for (int g = 0; g < 4; ++g){
    const int pl = wvid*64 + g*16 + n16;           // local pixel (LDS row)
    f16x8 Bh0 = *(const f16x8*)(&ybh_hi[pl][8*q]);
    f16x8 Bl0 = *(const f16x8*)(&ybh_lo[pl][8*q]);
    f16x8 Bh1 = *(const f16x8*)(&ybh_hi[pl][32 + 8*q]);
    f16x8 Bl1 = *(const f16x8*)(&ybh_lo[pl][32 + 8*q]);

    // GEMM1: h = relu(w1·y + b1); 4-product hi/lo = full fp32 fidelity
    #pragma unroll
    for (int ot = 0; ot < 8; ++ot){
      f32x4 acc = b1q[ot];
      acc = __builtin_amdgcn_mfma_f32_16x16x32_f16(A1h[ot][0], Bh0, acc, 0, 0, 0);
      acc = __builtin_amdgcn_mfma_f32_16x16x32_f16(A1h[ot][0], Bl0, acc, 0, 0, 0);
      acc = __builtin_amdgcn_mfma_f32_16x16x32_f16(A1l[ot][0], Bh0, acc, 0, 0, 0);
      acc = __builtin_amdgcn_mfma_f32_16x16x32_f16(A1l[ot][0], Bl0, acc, 0, 0, 0);
      acc = __builtin_amdgcn_mfma_f32_16x16x32_f16(A1h[ot][1], Bh1, acc, 0, 0, 0);
      acc = __builtin_amdgcn_mfma_f32_16x16x32_f16(A1h[ot][1], Bl1, acc, 0, 0, 0);
      acc = __builtin_amdgcn_mfma_f32_16x16x32_f16(A1l[ot][1], Bh1, acc, 0, 0, 0);
      acc = __builtin_amdgcn_mfma_f32_16x16x32_f16(A1l[ot][1], Bl1, acc, 0, 0, 0);
      f16x4 hh, hl;
      #pragma unroll
      for (int r = 0; r < 4; ++r){
        float hv = fmaxf(acc[r], 0.f);
        _Float16 h16 = (_Float16)hv;
        hh[r] = h16; hl[r] = (_Float16)(hv - (float)h16);
      }
      // lane holds h[o=16ot+4q+r][px=n16] -> store transposed [px][o]
      *(f16x4*)(&hb_hi[wvid][n16][16*ot + 4*q]) = hh;
      *(f16x4*)(&hb_lo[wvid][n16][16*ot + 4*q]) = hl;
    }

    // GEMM2: dx = w2·h; 4-product hi/lo
    f32x4 d2 = {0.f, 0.f, 0.f, 0.f};
    #pragma unroll
    for (int s = 0; s < 4; ++s){
      f16x8 B2h = *(const f16x8*)(&hb_hi[wvid][n16][32*s + 8*q]);
      f16x8 B2l = *(const f16x8*)(&hb_lo[wvid][n16][32*s + 8*q]);
      d2 = __builtin_amdgcn_mfma_f32_16x16x32_f16(A2h[s], B2h, d2, 0, 0, 0);
      d2 = __builtin_amdgcn_mfma_f32_16x16x32_f16(A2h[s], B2l, d2, 0, 0, 0);
      d2 = __builtin_amdgcn_mfma_f32_16x16x32_f16(A2l[s], B2h, d2, 0, 0, 0);
      d2 = __builtin_amdgcn_mfma_f32_16x16x32_f16(A2l[s], B2l, d2, 0, 0, 0);
    }

    const float f = (mr_row[pl] <= 0.5f) ? 1.f : 0.f;
    #pragma unroll
    for (int r = 0; r < 4; ++r){
      const int c = 4*q + r;
      const size_t idx = rowbase + (size_t)c*HW + (j0 + pl);
      const float xn = x[idx] + d2[r]*f;
      out[idx] = xn;
      if (c == 3) alpha_new[(size_t)b*HW + (size_t)i*W + (j0 + pl)] = xn;
    }
  }
}

__global__ __launch_bounds__(256) void k_life(
    const float* __restrict__ x, const float* __restrict__ alpha_new,
    float* __restrict__ out)
{
  int blk = blockIdx.x;
  int i = blk % H, b = blk / H;
  int j = threadIdx.x;
  const float* ax = x + ((size_t)b*C + 3)*HW;
  const float* an = alpha_new + (size_t)b*HW;
  float mpre = -1e30f, mpost = -1e30f;
  for (int di = -1; di <= 1; ++di){
    int ii = i + di; if (ii < 0 || ii >= H) continue;
    for (int dj = -1; dj <= 1; ++dj){
      int jj = j + dj; if (jj < 0 || jj >= W) continue;
      mpre  = fmaxf(mpre,  ax[ii*W+jj]);
      mpost = fmaxf(mpost, an[ii*W+jj]);
    }
  }
  bool life = (mpre > 0.1f) && (mpost > 0.1f);
  if (!life){
    size_t px = (size_t)b*C*HW + (size_t)i*W + j;
    #pragma unroll
    for (int m = 0; m < 16; ++m) out[px + (size_t)m*HW] = 0.f;
  }
}

extern "C" void kernel_launch(void* const* d_in, const int* in_sizes, int n_in,
                              void* d_out, int out_size, void* d_ws, size_t ws_size,
                              hipStream_t stream) {
  const float* x  = (const float*)d_in[0];
  const float* w1 = (const float*)d_in[1];
  const float* b1 = (const float*)d_in[2];
  const float* w2 = (const float*)d_in[3];
  const float* mr = (const float*)d_in[4];

  char* ws = (char*)d_ws;
  unsigned* mm     = (unsigned*)ws;                         // 256 B
  float* alpha_n   = (float*)(ws + 256);                    // 8 MB
  char* wb         = ws + 256 + (size_t)B*HW*4;
  _Float16* w1kh   = (_Float16*)(wb);                       // 16 KB
  _Float16* w1kl   = (_Float16*)(wb + 16384);               // 16 KB
  _Float16* w2hh   = (_Float16*)(wb + 32768);               // 4 KB
  _Float16* w2ll   = (_Float16*)(wb + 36864);               // 4 KB
  float* out       = (float*)d_out;

  k_prep  <<<1, 256, 0, stream>>>(w1, w2, mm, w1kh, w1kl, w2hh, w2ll);
  k_minmax<<<B*C*(H/ROWS), 256, 0, stream>>>(x, mm);
  k_main  <<<B*H*2, 128, 0, stream>>>(x, mr, mm, w1kh, w1kl, w2hh, w2ll,
                                      b1, out, alpha_n);
  k_life  <<<B*H, 256, 0, stream>>>(x, alpha_n, out);
}